// Round 3
// baseline (2592.919 us; speedup 1.0000x reference)
//
#include <hip/hip_runtime.h>
#include <math.h>

#define N_TOK 2000
#define NH 8
#define HD 32
#define SCALE 25.0f
#define SIM_TH 0.75f
#define EPSF 1e-8f
#define NSLOT 8   // ceil(2000/256)
#define NTAIL 208 // valid lanes in slot 7: 2000 - 7*256

// force a uniform value into an SGPR so dot-loop FMAs are v_fmac(v, s, v)
__device__ __forceinline__ float rfl(float x) {
  return __int_as_float(__builtin_amdgcn_readfirstlane(__float_as_int(x)));
}

__device__ __forceinline__ float block_max256(float v, float* red) {
#pragma unroll
  for (int off = 32; off > 0; off >>= 1) v = fmaxf(v, __shfl_xor(v, off, 64));
  __syncthreads();
  if ((threadIdx.x & 63) == 0) red[threadIdx.x >> 6] = v;
  __syncthreads();
  return fmaxf(fmaxf(red[0], red[1]), fmaxf(red[2], red[3]));
}
__device__ __forceinline__ float block_sum256(float v, float* red) {
#pragma unroll
  for (int off = 32; off > 0; off >>= 1) v += __shfl_xor(v, off, 64);
  __syncthreads();
  if ((threadIdx.x & 63) == 0) red[threadIdx.x >> 6] = v;
  __syncthreads();
  return (red[0] + red[1]) + (red[2] + red[3]);
}

// ---------------------------------------------------------------------------
// Kernel 1: QKV projection + l2norm (unchanged from round 2; ~70 us).
// grid = (500, 2), block = 256
// ---------------------------------------------------------------------------
__global__ __launch_bounds__(256) void qkv_norm_kernel(
    const float* __restrict__ x_cls, const float* __restrict__ x_reg,
    const float* __restrict__ W_cls, const float* __restrict__ W_reg,
    float* __restrict__ qn_cls, float* __restrict__ qn_reg,
    float* __restrict__ kct, float* __restrict__ krt,
    float* __restrict__ vnt, float* __restrict__ v_rm) {
  __shared__ float xs[4][256];
  __shared__ float res[4][768];
  __shared__ float inv_norm[96];

  const int n0 = blockIdx.x * 4;
  const int which = blockIdx.y;
  const int tid = threadIdx.x;
  const float* __restrict__ x = which ? x_reg : x_cls;
  const float* __restrict__ W = which ? W_reg : W_cls;

#pragma unroll
  for (int r = 0; r < 4; r++) xs[r][tid] = x[(n0 + r) * 256 + tid];
  __syncthreads();

  float acc[4][3];
#pragma unroll
  for (int r = 0; r < 4; r++) acc[r][0] = acc[r][1] = acc[r][2] = 0.f;

  for (int k = 0; k < 256; k++) {
    const float* __restrict__ wr = W + k * 768;
    const float w0 = wr[tid], w1 = wr[tid + 256], w2 = wr[tid + 512];
#pragma unroll
    for (int r = 0; r < 4; r++) {
      const float xv = xs[r][k];
      acc[r][0] += xv * w0;
      acc[r][1] += xv * w1;
      acc[r][2] += xv * w2;
    }
  }
#pragma unroll
  for (int r = 0; r < 4; r++) {
    res[r][tid] = acc[r][0];
    res[r][tid + 256] = acc[r][1];
    res[r][tid + 512] = acc[r][2];
  }
  __syncthreads();

  if (tid < 96) {
    const int r = tid / 24, grp = tid % 24;
    float ss = 0.f;
#pragma unroll
    for (int d = 0; d < HD; d++) {
      const float v = res[r][grp * 32 + d];
      ss += v * v;
    }
    inv_norm[tid] = 1.0f / (sqrtf(ss) + EPSF);
  }
  __syncthreads();

#pragma unroll
  for (int j = 0; j < 3; j++) {
    const int c = tid + j * 256;
    const int qkv = c >> 8, grp = c >> 5;
    const int h = grp & 7, d = c & 31;
    const int g = d >> 2, comp = d & 3;
#pragma unroll
    for (int r = 0; r < 4; r++) {
      const int n = n0 + r;
      const float val = res[r][c];
      const float nval = val * inv_norm[r * 24 + grp];
      if (qkv == 0) {
        (which ? qn_reg : qn_cls)[(h * N_TOK + n) * HD + d] = nval;
      } else if (qkv == 1) {
        (which ? krt : kct)[((h * 8 + g) * N_TOK + n) * 4 + comp] = nval;
      } else if (which == 0) {
        v_rm[(h * N_TOK + n) * HD + d] = val;
        vnt[((h * 8 + g) * N_TOK + n) * 4 + comp] = nval;
      }
    }
  }
}

// ---------------------------------------------------------------------------
// Kernel 2: 2 query rows per block. sim/raw accumulators in per-thread
// REGISTER slots (m = tid + 256*t); LDS only for s_attn (PV input) + part4.
// LDS ~24.6KB, target VGPR<=128 -> 4 blocks/CU (16 waves/CU).
// grid = 1000, block = 256
// ---------------------------------------------------------------------------
__global__ __launch_bounds__(256, 4) void attn3_kernel(
    const float* __restrict__ qn_cls, const float* __restrict__ qn_reg,
    const float* __restrict__ kct, const float* __restrict__ krt,
    const float* __restrict__ vnt, const float* __restrict__ v_rm,
    float* __restrict__ out_x, float* __restrict__ out_sim) {
  __shared__ float s_attn[2 * N_TOK];
  __shared__ float4 part4[32][2][8];
  __shared__ float red[4];

  const int tid = threadIdx.x;
  const int i0 = blockIdx.x * 2;
  const int i1 = i0 + 1;
  const int bs = (i0 / 10) * 10;  // i0 even -> i0,i1 share the same decade

  // persistent per-thread accumulators (register slots, m = tid + 256*t)
  float sim0[NSLOT], sim1[NSLOT], raw0[NSLOT], raw1[NSLOT];
#pragma unroll
  for (int t = 0; t < NSLOT; t++) {
    sim0[t] = 0.f; sim1[t] = 0.f; raw0[t] = 0.f; raw1[t] = 0.f;
  }

  float q0[HD], q1[HD];       // wave-uniform -> SGPRs
  float sc0[NSLOT], sc1[NSLOT];

  for (int h = 0; h < NH; h++) {
    // ============ phase C: cls scores -> s_attn = 0.5*softmax ============
    {
      const float* __restrict__ p0 = qn_cls + (size_t)(h * N_TOK + i0) * HD;
      const float* __restrict__ p1 = qn_cls + (size_t)(h * N_TOK + i1) * HD;
#pragma unroll
      for (int d = 0; d < HD; d++) { q0[d] = rfl(p0[d]); q1[d] = rfl(p1[d]); }
    }
    float lm0 = -1e30f, lm1 = -1e30f;
    {
      const float4* __restrict__ kt4 = (const float4*)kct + (size_t)h * 8 * N_TOK;
#pragma unroll
      for (int t = 0; t < NSLOT; t++) {
        const int m = tid + 256 * t;
        const bool valid = (t < 7) || (tid < NTAIL);
        const int mc = valid ? m : (N_TOK - 1);
        float4 kv[8];
#pragma unroll
        for (int g = 0; g < 8; g++) kv[g] = kt4[g * N_TOK + mc];
        float d0 = 0.f, d1 = 0.f;
#pragma unroll
        for (int g = 0; g < 8; g++) {
          d0 += q0[4 * g] * kv[g].x + q0[4 * g + 1] * kv[g].y +
                q0[4 * g + 2] * kv[g].z + q0[4 * g + 3] * kv[g].w;
          d1 += q1[4 * g] * kv[g].x + q1[4 * g + 1] * kv[g].y +
                q1[4 * g + 2] * kv[g].z + q1[4 * g + 3] * kv[g].w;
        }
        d0 *= SCALE; d1 *= SCALE;
        if (!valid) { d0 = -1e30f; d1 = -1e30f; }
        sc0[t] = d0; sc1[t] = d1;
        lm0 = fmaxf(lm0, d0); lm1 = fmaxf(lm1, d1);
      }
    }
    const float M0c = block_max256(lm0, red);
    const float M1c = block_max256(lm1, red);
    float ls0 = 0.f, ls1 = 0.f;
#pragma unroll
    for (int t = 0; t < NSLOT; t++) {
      sc0[t] = expf(sc0[t] - M0c);  // invalid slots -> exp(-huge) = 0
      sc1[t] = expf(sc1[t] - M1c);
      ls0 += sc0[t]; ls1 += sc1[t];
    }
    const float S0c = block_sum256(ls0, red);
    const float S1c = block_sum256(ls1, red);
    const float n0c = 0.5f / S0c, n1c = 0.5f / S1c;
#pragma unroll
    for (int t = 0; t < NSLOT; t++) {
      const int m = tid + 256 * t;
      if ((t < 7) || (tid < NTAIL)) {
        s_attn[m] = sc0[t] * n0c;
        s_attn[N_TOK + m] = sc1[t] * n1c;
      }
    }

    // ============ phase R: reg scores, combine, mask, sim += ============
    {
      const float* __restrict__ p0 = qn_reg + (size_t)(h * N_TOK + i0) * HD;
      const float* __restrict__ p1 = qn_reg + (size_t)(h * N_TOK + i1) * HD;
#pragma unroll
      for (int d = 0; d < HD; d++) { q0[d] = rfl(p0[d]); q1[d] = rfl(p1[d]); }
    }
    lm0 = -1e30f; lm1 = -1e30f;
    {
      const float4* __restrict__ kt4 = (const float4*)krt + (size_t)h * 8 * N_TOK;
#pragma unroll
      for (int t = 0; t < NSLOT; t++) {
        const int m = tid + 256 * t;
        const bool valid = (t < 7) || (tid < NTAIL);
        const int mc = valid ? m : (N_TOK - 1);
        float4 kv[8];
#pragma unroll
        for (int g = 0; g < 8; g++) kv[g] = kt4[g * N_TOK + mc];
        float d0 = 0.f, d1 = 0.f;
#pragma unroll
        for (int g = 0; g < 8; g++) {
          d0 += q0[4 * g] * kv[g].x + q0[4 * g + 1] * kv[g].y +
                q0[4 * g + 2] * kv[g].z + q0[4 * g + 3] * kv[g].w;
          d1 += q1[4 * g] * kv[g].x + q1[4 * g + 1] * kv[g].y +
                q1[4 * g + 2] * kv[g].z + q1[4 * g + 3] * kv[g].w;
        }
        d0 *= SCALE; d1 *= SCALE;
        if (!valid) { d0 = -1e30f; d1 = -1e30f; }
        sc0[t] = d0; sc1[t] = d1;
        lm0 = fmaxf(lm0, d0); lm1 = fmaxf(lm1, d1);
      }
    }
    const float M0r = block_max256(lm0, red);
    const float M1r = block_max256(lm1, red);
    ls0 = 0.f; ls1 = 0.f;
#pragma unroll
    for (int t = 0; t < NSLOT; t++) {
      sc0[t] = expf(sc0[t] - M0r);
      sc1[t] = expf(sc1[t] - M1r);
      ls0 += sc0[t]; ls1 += sc1[t];
    }
    const float S0r = block_sum256(ls0, red);
    const float S1r = block_sum256(ls1, red);
    const float n0r = 0.5f / S0r, n1r = 0.5f / S1r;
#pragma unroll
    for (int t = 0; t < NSLOT; t++) {
      const int m = tid + 256 * t;
      if ((t < 7) || (tid < NTAIL)) {
        float a0 = s_attn[m] + sc0[t] * n0r;
        float a1 = s_attn[N_TOK + m] + sc1[t] * n1r;
        if (m >= bs && m < bs + 9) {
          if (m != i0) a0 = 0.f;
          if (m != i1) a1 = 0.f;
        }
        s_attn[m] = a0;
        s_attn[N_TOK + m] = a1;
        sim0[t] += a0;
        sim1[t] += a1;
      }
    }

    // ============ phase V: vn cosine -> raw += ============
    {
#pragma unroll
      for (int d = 0; d < HD; d++) {
        const int g = d >> 2, comp = d & 3;
        q0[d] = rfl(vnt[((size_t)(h * 8 + g) * N_TOK + i0) * 4 + comp]);
        q1[d] = rfl(vnt[((size_t)(h * 8 + g) * N_TOK + i1) * 4 + comp]);
      }
      const float4* __restrict__ kt4 = (const float4*)vnt + (size_t)h * 8 * N_TOK;
#pragma unroll
      for (int t = 0; t < NSLOT; t++) {
        const int m = tid + 256 * t;
        const bool valid = (t < 7) || (tid < NTAIL);
        const int mc = valid ? m : (N_TOK - 1);
        float4 kv[8];
#pragma unroll
        for (int g = 0; g < 8; g++) kv[g] = kt4[g * N_TOK + mc];
        float d0 = 0.f, d1 = 0.f;
#pragma unroll
        for (int g = 0; g < 8; g++) {
          d0 += q0[4 * g] * kv[g].x + q0[4 * g + 1] * kv[g].y +
                q0[4 * g + 2] * kv[g].z + q0[4 * g + 3] * kv[g].w;
          d1 += q1[4 * g] * kv[g].x + q1[4 * g + 1] * kv[g].y +
                q1[4 * g + 2] * kv[g].z + q1[4 * g + 3] * kv[g].w;
        }
        if (valid) { raw0[t] += d0; raw1[t] += d1; }
      }
    }
    __syncthreads();  // s_attn final for this head

    // ============ attn @ V ============
    {
      const int g2 = tid & 7, slice = tid >> 3;
      const int m0 = slice * 63;
      const int mend = (m0 + 63 < N_TOK) ? (m0 + 63) : N_TOK;
      float4 a0acc = {0.f, 0.f, 0.f, 0.f}, a1acc = {0.f, 0.f, 0.f, 0.f};
      const float4* __restrict__ v4 = (const float4*)v_rm + (size_t)h * N_TOK * 8;
      for (int m = m0; m < mend; m++) {
        const float4 vv = v4[m * 8 + g2];
        const float a0 = s_attn[m];
        const float a1 = s_attn[N_TOK + m];
        a0acc.x += a0 * vv.x; a0acc.y += a0 * vv.y;
        a0acc.z += a0 * vv.z; a0acc.w += a0 * vv.w;
        a1acc.x += a1 * vv.x; a1acc.y += a1 * vv.y;
        a1acc.z += a1 * vv.z; a1acc.w += a1 * vv.w;
      }
      part4[slice][0][g2] = a0acc;
      part4[slice][1][g2] = a1acc;
    }
    __syncthreads();
    if (tid < 16) {
      const int q = tid >> 3, g = tid & 7;
      float4 s = {0.f, 0.f, 0.f, 0.f};
#pragma unroll 8
      for (int sl = 0; sl < 32; sl++) {
        const float4 p = part4[sl][q][g];
        s.x += p.x; s.y += p.y; s.z += p.z; s.w += p.w;
      }
      const int irow = q ? i1 : i0;
      *(float4*)(out_x + (size_t)irow * 512 + h * 32 + 4 * g) = s;
    } else if (tid >= 64 && tid < 128) {
      const int q = (tid - 64) >> 5, d = (tid - 64) & 31;
      const int irow = q ? i1 : i0;
      out_x[(size_t)irow * 512 + 256 + h * 32 + d] =
          v_rm[((size_t)h * N_TOK + irow) * HD + d];
    }
    __syncthreads();  // protect s_attn/part4 before next head
  }

  // ============ sim_round2 epilogue, entirely from registers ============
#pragma unroll
  for (int q = 0; q < 2; q++) {
    const int irow = q ? i1 : i0;
    float* __restrict__ sim = q ? sim1 : sim0;
    float* __restrict__ raw = q ? raw1 : raw0;

    float lm = -1e30f;
#pragma unroll
    for (int t = 0; t < NSLOT; t++) {
      const bool valid = (t < 7) || (tid < NTAIL);
      if (valid) lm = fmaxf(lm, sim[t] * 0.125f);
    }
    const float M = block_max256(lm, red);

    float ls = 0.f;
#pragma unroll
    for (int t = 0; t < NSLOT; t++) {
      const bool valid = (t < 7) || (tid < NTAIL);
      const float e = valid ? expf(sim[t] * 0.125f - M) : 0.f;
      sim[t] = e;
      ls += e;
    }
    const float S = block_sum256(ls, red);
    const float invS = 1.0f / S;

    float lms = 0.f;
#pragma unroll
    for (int t = 0; t < NSLOT; t++) {
      const bool valid = (t < 7) || (tid < NTAIL);
      const float p = sim[t] * invS;
      const float mp = (valid && (raw[t] * 0.125f > SIM_TH)) ? p : 0.f;
      sim[t] = mp;
      lms += mp;
    }
    const float MS = block_sum256(lms, red);
    const float invMS = 1.0f / (MS + EPSF);

#pragma unroll
    for (int t = 0; t < NSLOT; t++) {
      const int m = tid + 256 * t;
      if ((t < 7) || (tid < NTAIL)) {
        out_sim[(size_t)irow * N_TOK + m] = sim[t] * invMS;
      }
    }
  }
}

// ---------------------------------------------------------------------------
extern "C" void kernel_launch(void* const* d_in, const int* in_sizes, int n_in,
                              void* d_out, int out_size, void* d_ws,
                              size_t ws_size, hipStream_t stream) {
  const float* x_cls = (const float*)d_in[0];
  const float* x_reg = (const float*)d_in[1];
  const float* W_cls = (const float*)d_in[2];
  const float* W_reg = (const float*)d_in[3];

  float* ws = (float*)d_ws;
  const size_t seg = (size_t)NH * N_TOK * HD;  // 512000 floats
  float* qn_cls = ws;
  float* qn_reg = qn_cls + seg;
  float* kct = qn_reg + seg;
  float* krt = kct + seg;
  float* vnt = krt + seg;
  float* v_rm = vnt + seg;

  dim3 g1(500, 2);
  qkv_norm_kernel<<<g1, 256, 0, stream>>>(x_cls, x_reg, W_cls, W_reg, qn_cls,
                                          qn_reg, kct, krt, vnt, v_rm);

  float* out_x = (float*)d_out;                  // [2000, 512]
  float* out_sim = out_x + (size_t)N_TOK * 512;  // [2000, 2000]
  attn3_kernel<<<1000, 256, 0, stream>>>(qn_cls, qn_reg, kct, krt, vnt, v_rm,
                                         out_x, out_sim);
}

// Round 4
// 1780.878 us; speedup vs baseline: 1.4560x; 1.4560x over previous
//
#include <hip/hip_runtime.h>
#include <math.h>

#define N_TOK 2000
#define NH 8
#define HD 32
#define SCALE 25.0f
#define SIM_TH 0.75f
#define EPSF 1e-8f
#define NSLOT 8   // ceil(2000/256)
#define NTAIL 208 // valid lanes in slot 7: 2000 - 7*256

// force a uniform value into an SGPR so dot-loop FMAs are v_fmac(v, s, v)
__device__ __forceinline__ float rfl(float x) {
  return __int_as_float(__builtin_amdgcn_readfirstlane(__float_as_int(x)));
}

__device__ __forceinline__ float block_max256(float v, float* red) {
#pragma unroll
  for (int off = 32; off > 0; off >>= 1) v = fmaxf(v, __shfl_xor(v, off, 64));
  __syncthreads();
  if ((threadIdx.x & 63) == 0) red[threadIdx.x >> 6] = v;
  __syncthreads();
  return fmaxf(fmaxf(red[0], red[1]), fmaxf(red[2], red[3]));
}
__device__ __forceinline__ float block_sum256(float v, float* red) {
#pragma unroll
  for (int off = 32; off > 0; off >>= 1) v += __shfl_xor(v, off, 64);
  __syncthreads();
  if ((threadIdx.x & 63) == 0) red[threadIdx.x >> 6] = v;
  __syncthreads();
  return (red[0] + red[1]) + (red[2] + red[3]);
}

// dot of uniform q[32] (SGPR) against 8 float4 stream slices, split 4+4 to
// cap in-flight load registers.
#define DOT_BODY(kt4, mc, d0, d1)                                         \
  {                                                                       \
    float4 kv[4];                                                         \
    _Pragma("unroll") for (int g = 0; g < 4; g++) kv[g] =                 \
        kt4[g * N_TOK + (mc)];                                            \
    _Pragma("unroll") for (int g = 0; g < 4; g++) {                       \
      d0 += q0[4 * g] * kv[g].x + q0[4 * g + 1] * kv[g].y +               \
            q0[4 * g + 2] * kv[g].z + q0[4 * g + 3] * kv[g].w;            \
      d1 += q1[4 * g] * kv[g].x + q1[4 * g + 1] * kv[g].y +               \
            q1[4 * g + 2] * kv[g].z + q1[4 * g + 3] * kv[g].w;            \
    }                                                                     \
    _Pragma("unroll") for (int g = 0; g < 4; g++) kv[g] =                 \
        kt4[(g + 4) * N_TOK + (mc)];                                      \
    _Pragma("unroll") for (int g = 0; g < 4; g++) {                       \
      d0 += q0[4 * g + 16] * kv[g].x + q0[4 * g + 17] * kv[g].y +         \
            q0[4 * g + 18] * kv[g].z + q0[4 * g + 19] * kv[g].w;          \
      d1 += q1[4 * g + 16] * kv[g].x + q1[4 * g + 17] * kv[g].y +         \
            q1[4 * g + 18] * kv[g].z + q1[4 * g + 19] * kv[g].w;          \
    }                                                                     \
  }

// ---------------------------------------------------------------------------
// Kernel 1: QKV projection + l2norm (unchanged; ~70 us).
// grid = (500, 2), block = 256
// ---------------------------------------------------------------------------
__global__ __launch_bounds__(256) void qkv_norm_kernel(
    const float* __restrict__ x_cls, const float* __restrict__ x_reg,
    const float* __restrict__ W_cls, const float* __restrict__ W_reg,
    float* __restrict__ qn_cls, float* __restrict__ qn_reg,
    float* __restrict__ kct, float* __restrict__ krt,
    float* __restrict__ vnt, float* __restrict__ v_rm) {
  __shared__ float xs[4][256];
  __shared__ float res[4][768];
  __shared__ float inv_norm[96];

  const int n0 = blockIdx.x * 4;
  const int which = blockIdx.y;
  const int tid = threadIdx.x;
  const float* __restrict__ x = which ? x_reg : x_cls;
  const float* __restrict__ W = which ? W_reg : W_cls;

#pragma unroll
  for (int r = 0; r < 4; r++) xs[r][tid] = x[(n0 + r) * 256 + tid];
  __syncthreads();

  float acc[4][3];
#pragma unroll
  for (int r = 0; r < 4; r++) acc[r][0] = acc[r][1] = acc[r][2] = 0.f;

  for (int k = 0; k < 256; k++) {
    const float* __restrict__ wr = W + k * 768;
    const float w0 = wr[tid], w1 = wr[tid + 256], w2 = wr[tid + 512];
#pragma unroll
    for (int r = 0; r < 4; r++) {
      const float xv = xs[r][k];
      acc[r][0] += xv * w0;
      acc[r][1] += xv * w1;
      acc[r][2] += xv * w2;
    }
  }
#pragma unroll
  for (int r = 0; r < 4; r++) {
    res[r][tid] = acc[r][0];
    res[r][tid + 256] = acc[r][1];
    res[r][tid + 512] = acc[r][2];
  }
  __syncthreads();

  if (tid < 96) {
    const int r = tid / 24, grp = tid % 24;
    float ss = 0.f;
#pragma unroll
    for (int d = 0; d < HD; d++) {
      const float v = res[r][grp * 32 + d];
      ss += v * v;
    }
    inv_norm[tid] = 1.0f / (sqrtf(ss) + EPSF);
  }
  __syncthreads();

#pragma unroll
  for (int j = 0; j < 3; j++) {
    const int c = tid + j * 256;
    const int qkv = c >> 8, grp = c >> 5;
    const int h = grp & 7, d = c & 31;
    const int g = d >> 2, comp = d & 3;
#pragma unroll
    for (int r = 0; r < 4; r++) {
      const int n = n0 + r;
      const float val = res[r][c];
      const float nval = val * inv_norm[r * 24 + grp];
      if (qkv == 0) {
        (which ? qn_reg : qn_cls)[(h * N_TOK + n) * HD + d] = nval;
      } else if (qkv == 1) {
        (which ? krt : kct)[((h * 8 + g) * N_TOK + n) * 4 + comp] = nval;
      } else if (which == 0) {
        v_rm[(h * N_TOK + n) * HD + d] = val;
        vnt[((h * 8 + g) * N_TOK + n) * 4 + comp] = nval;
      }
    }
  }
}

// ---------------------------------------------------------------------------
// Kernel 2: 2 query rows per block. Fixed-shift softmax (score<=25 exactly,
// shift-invariant) -> no max pass, no cls score persistence. sim/raw in
// per-thread register slots. LDS 24.6KB; VGPR target <128 -> 4 blocks/CU.
// grid = 1000, block = 256
// ---------------------------------------------------------------------------
__global__ __launch_bounds__(256, 4) void attn4_kernel(
    const float* __restrict__ qn_cls, const float* __restrict__ qn_reg,
    const float* __restrict__ kct, const float* __restrict__ krt,
    const float* __restrict__ vnt, const float* __restrict__ v_rm,
    float* __restrict__ out_x, float* __restrict__ out_sim) {
  __shared__ float s_attn[2 * N_TOK];
  __shared__ float4 part4[32][2][8];
  __shared__ float red[4];

  const int tid = threadIdx.x;
  const int i0 = blockIdx.x * 2;
  const int i1 = i0 + 1;
  const int bs = (i0 / 10) * 10;  // i0 even -> i0,i1 share the same decade

  // persistent per-thread accumulators (register slots, m = tid + 256*t)
  float sim0[NSLOT], sim1[NSLOT], raw0[NSLOT], raw1[NSLOT];
#pragma unroll
  for (int t = 0; t < NSLOT; t++) {
    sim0[t] = 0.f; sim1[t] = 0.f; raw0[t] = 0.f; raw1[t] = 0.f;
  }

  float q0[HD], q1[HD];        // wave-uniform -> SGPRs
  float er0[NSLOT], er1[NSLOT];  // reg-stream exp values (one pair only)

  for (int h = 0; h < NH; h++) {
    // ===== phase C: cls scores -> e = exp(s-25) -> s_attn (unnormalized) ===
    {
      const float* __restrict__ p0 = qn_cls + (size_t)(h * N_TOK + i0) * HD;
      const float* __restrict__ p1 = qn_cls + (size_t)(h * N_TOK + i1) * HD;
#pragma unroll
      for (int d = 0; d < HD; d++) { q0[d] = rfl(p0[d]); q1[d] = rfl(p1[d]); }
    }
    float ls0 = 0.f, ls1 = 0.f;
    {
      const float4* __restrict__ kt4 = (const float4*)kct + (size_t)h * 8 * N_TOK;
#pragma unroll
      for (int t = 0; t < NSLOT; t++) {
        const int m = tid + 256 * t;
        const bool valid = (t < 7) || (tid < NTAIL);
        const int mc = valid ? m : (N_TOK - 1);
        float d0 = 0.f, d1 = 0.f;
        DOT_BODY(kt4, mc, d0, d1);
        const float e0 = valid ? __expf(d0 * SCALE - SCALE) : 0.f;
        const float e1 = valid ? __expf(d1 * SCALE - SCALE) : 0.f;
        ls0 += e0; ls1 += e1;
        if (valid) {
          s_attn[m] = e0;
          s_attn[N_TOK + m] = e1;
        }
      }
    }
    const float S0c = block_sum256(ls0, red);
    const float S1c = block_sum256(ls1, red);
    const float n0c = 0.5f / S0c, n1c = 0.5f / S1c;

    // ===== phase R: reg scores -> er regs =====
    {
      const float* __restrict__ p0 = qn_reg + (size_t)(h * N_TOK + i0) * HD;
      const float* __restrict__ p1 = qn_reg + (size_t)(h * N_TOK + i1) * HD;
#pragma unroll
      for (int d = 0; d < HD; d++) { q0[d] = rfl(p0[d]); q1[d] = rfl(p1[d]); }
    }
    float lr0 = 0.f, lr1 = 0.f;
    {
      const float4* __restrict__ kt4 = (const float4*)krt + (size_t)h * 8 * N_TOK;
#pragma unroll
      for (int t = 0; t < NSLOT; t++) {
        const int m = tid + 256 * t;
        const bool valid = (t < 7) || (tid < NTAIL);
        const int mc = valid ? m : (N_TOK - 1);
        float d0 = 0.f, d1 = 0.f;
        DOT_BODY(kt4, mc, d0, d1);
        const float e0 = valid ? __expf(d0 * SCALE - SCALE) : 0.f;
        const float e1 = valid ? __expf(d1 * SCALE - SCALE) : 0.f;
        er0[t] = e0; er1[t] = e1;
        lr0 += e0; lr1 += e1;
      }
    }
    const float S0r = block_sum256(lr0, red);
    const float S1r = block_sum256(lr1, red);
    const float n0r = 0.5f / S0r, n1r = 0.5f / S1r;

    // ===== combine, mask, sim += =====
#pragma unroll
    for (int t = 0; t < NSLOT; t++) {
      const int m = tid + 256 * t;
      if ((t < 7) || (tid < NTAIL)) {
        float a0 = s_attn[m] * n0c + er0[t] * n0r;
        float a1 = s_attn[N_TOK + m] * n1c + er1[t] * n1r;
        if (m >= bs && m < bs + 9) {
          if (m != i0) a0 = 0.f;
          if (m != i1) a1 = 0.f;
        }
        s_attn[m] = a0;
        s_attn[N_TOK + m] = a1;
        sim0[t] += a0;
        sim1[t] += a1;
      }
    }

    // ===== phase V: vn cosine -> raw += =====
    {
#pragma unroll
      for (int d = 0; d < HD; d++) {
        const int g = d >> 2, comp = d & 3;
        q0[d] = rfl(vnt[((size_t)(h * 8 + g) * N_TOK + i0) * 4 + comp]);
        q1[d] = rfl(vnt[((size_t)(h * 8 + g) * N_TOK + i1) * 4 + comp]);
      }
      const float4* __restrict__ kt4 = (const float4*)vnt + (size_t)h * 8 * N_TOK;
#pragma unroll
      for (int t = 0; t < NSLOT; t++) {
        const int m = tid + 256 * t;
        const bool valid = (t < 7) || (tid < NTAIL);
        const int mc = valid ? m : (N_TOK - 1);
        float d0 = 0.f, d1 = 0.f;
        DOT_BODY(kt4, mc, d0, d1);
        if (valid) { raw0[t] += d0; raw1[t] += d1; }
      }
    }
    __syncthreads();  // s_attn final for this head

    // ===== attn @ V =====
    {
      const int g2 = tid & 7, slice = tid >> 3;
      const int m0 = slice * 63;
      const int mend = (m0 + 63 < N_TOK) ? (m0 + 63) : N_TOK;
      float4 a0acc = {0.f, 0.f, 0.f, 0.f}, a1acc = {0.f, 0.f, 0.f, 0.f};
      const float4* __restrict__ v4 = (const float4*)v_rm + (size_t)h * N_TOK * 8;
      for (int m = m0; m < mend; m++) {
        const float4 vv = v4[m * 8 + g2];
        const float a0 = s_attn[m];
        const float a1 = s_attn[N_TOK + m];
        a0acc.x += a0 * vv.x; a0acc.y += a0 * vv.y;
        a0acc.z += a0 * vv.z; a0acc.w += a0 * vv.w;
        a1acc.x += a1 * vv.x; a1acc.y += a1 * vv.y;
        a1acc.z += a1 * vv.z; a1acc.w += a1 * vv.w;
      }
      part4[slice][0][g2] = a0acc;
      part4[slice][1][g2] = a1acc;
    }
    __syncthreads();
    if (tid < 16) {
      const int q = tid >> 3, g = tid & 7;
      float4 s = {0.f, 0.f, 0.f, 0.f};
#pragma unroll 8
      for (int sl = 0; sl < 32; sl++) {
        const float4 p = part4[sl][q][g];
        s.x += p.x; s.y += p.y; s.z += p.z; s.w += p.w;
      }
      const int irow = q ? i1 : i0;
      *(float4*)(out_x + (size_t)irow * 512 + h * 32 + 4 * g) = s;
    } else if (tid >= 64 && tid < 128) {
      const int q = (tid - 64) >> 5, d = (tid - 64) & 31;
      const int irow = q ? i1 : i0;
      out_x[(size_t)irow * 512 + 256 + h * 32 + d] =
          v_rm[((size_t)h * N_TOK + irow) * HD + d];
    }
    __syncthreads();  // protect s_attn/part4 before next head
  }

  // ===== sim_round2 epilogue, from registers =====
#pragma unroll
  for (int q = 0; q < 2; q++) {
    const int irow = q ? i1 : i0;
    float* __restrict__ sim = q ? sim1 : sim0;
    float* __restrict__ raw = q ? raw1 : raw0;

    float lm = -1e30f;
#pragma unroll
    for (int t = 0; t < NSLOT; t++) {
      if ((t < 7) || (tid < NTAIL)) lm = fmaxf(lm, sim[t] * 0.125f);
    }
    const float M = block_max256(lm, red);

    float ls = 0.f;
#pragma unroll
    for (int t = 0; t < NSLOT; t++) {
      const bool valid = (t < 7) || (tid < NTAIL);
      const float e = valid ? __expf(sim[t] * 0.125f - M) : 0.f;
      sim[t] = e;
      ls += e;
    }
    const float S = block_sum256(ls, red);
    const float invS = 1.0f / S;

    float lms = 0.f;
#pragma unroll
    for (int t = 0; t < NSLOT; t++) {
      const bool valid = (t < 7) || (tid < NTAIL);
      const float p = sim[t] * invS;
      const float mp = (valid && (raw[t] * 0.125f > SIM_TH)) ? p : 0.f;
      sim[t] = mp;
      lms += mp;
    }
    const float MS = block_sum256(lms, red);
    const float invMS = 1.0f / (MS + EPSF);

#pragma unroll
    for (int t = 0; t < NSLOT; t++) {
      const int m = tid + 256 * t;
      if ((t < 7) || (tid < NTAIL)) {
        out_sim[(size_t)irow * N_TOK + m] = sim[t] * invMS;
      }
    }
  }
}

// ---------------------------------------------------------------------------
extern "C" void kernel_launch(void* const* d_in, const int* in_sizes, int n_in,
                              void* d_out, int out_size, void* d_ws,
                              size_t ws_size, hipStream_t stream) {
  const float* x_cls = (const float*)d_in[0];
  const float* x_reg = (const float*)d_in[1];
  const float* W_cls = (const float*)d_in[2];
  const float* W_reg = (const float*)d_in[3];

  float* ws = (float*)d_ws;
  const size_t seg = (size_t)NH * N_TOK * HD;  // 512000 floats
  float* qn_cls = ws;
  float* qn_reg = qn_cls + seg;
  float* kct = qn_reg + seg;
  float* krt = kct + seg;
  float* vnt = krt + seg;
  float* v_rm = vnt + seg;

  dim3 g1(500, 2);
  qkv_norm_kernel<<<g1, 256, 0, stream>>>(x_cls, x_reg, W_cls, W_reg, qn_cls,
                                          qn_reg, kct, krt, vnt, v_rm);

  float* out_x = (float*)d_out;                  // [2000, 512]
  float* out_sim = out_x + (size_t)N_TOK * 512;  // [2000, 2000]
  attn4_kernel<<<1000, 256, 0, stream>>>(qn_cls, qn_reg, kct, krt, vnt, v_rm,
                                         out_x, out_sim);
}

// Round 5
// 1322.374 us; speedup vs baseline: 1.9608x; 1.3467x over previous
//
#include <hip/hip_runtime.h>
#include <math.h>

#define N_TOK 2000
#define NH 8
#define HD 32
#define SCALE 25.0f
#define SIM_TH 0.75f
#define EPSF 1e-8f
#define NSLOT 8   // ceil(2000/256)
#define NTAIL 208 // valid lanes in slot 7: 2000 - 7*256

// force a uniform value into an SGPR so dot-loop FMAs are v_fmac(v, s, v)
__device__ __forceinline__ float rfl(float x) {
  return __int_as_float(__builtin_amdgcn_readfirstlane(__float_as_int(x)));
}

__device__ __forceinline__ float block_max256(float v, float* red) {
#pragma unroll
  for (int off = 32; off > 0; off >>= 1) v = fmaxf(v, __shfl_xor(v, off, 64));
  __syncthreads();
  if ((threadIdx.x & 63) == 0) red[threadIdx.x >> 6] = v;
  __syncthreads();
  return fmaxf(fmaxf(red[0], red[1]), fmaxf(red[2], red[3]));
}
__device__ __forceinline__ float block_sum256(float v, float* red) {
#pragma unroll
  for (int off = 32; off > 0; off >>= 1) v += __shfl_xor(v, off, 64);
  __syncthreads();
  if ((threadIdx.x & 63) == 0) red[threadIdx.x >> 6] = v;
  __syncthreads();
  return (red[0] + red[1]) + (red[2] + red[3]);
}

// dot of uniform q[32] (SGPR) against 8 float4 stream slices, split 4+4 to
// cap in-flight load registers.
#define DOT_BODY(kt4, mc, d0, d1)                                         \
  {                                                                       \
    float4 kv[4];                                                         \
    _Pragma("unroll") for (int g = 0; g < 4; g++) kv[g] =                 \
        kt4[g * N_TOK + (mc)];                                            \
    _Pragma("unroll") for (int g = 0; g < 4; g++) {                       \
      d0 += q0[4 * g] * kv[g].x + q0[4 * g + 1] * kv[g].y +               \
            q0[4 * g + 2] * kv[g].z + q0[4 * g + 3] * kv[g].w;            \
      d1 += q1[4 * g] * kv[g].x + q1[4 * g + 1] * kv[g].y +               \
            q1[4 * g + 2] * kv[g].z + q1[4 * g + 3] * kv[g].w;            \
    }                                                                     \
    _Pragma("unroll") for (int g = 0; g < 4; g++) kv[g] =                 \
        kt4[(g + 4) * N_TOK + (mc)];                                      \
    _Pragma("unroll") for (int g = 0; g < 4; g++) {                       \
      d0 += q0[4 * g + 16] * kv[g].x + q0[4 * g + 17] * kv[g].y +         \
            q0[4 * g + 18] * kv[g].z + q0[4 * g + 19] * kv[g].w;          \
      d1 += q1[4 * g + 16] * kv[g].x + q1[4 * g + 17] * kv[g].y +         \
            q1[4 * g + 18] * kv[g].z + q1[4 * g + 19] * kv[g].w;          \
    }                                                                     \
  }

// ---------------------------------------------------------------------------
// Kernel 1: QKV projection + l2norm (unchanged; ~70 us).
// grid = (500, 2), block = 256
// ---------------------------------------------------------------------------
__global__ __launch_bounds__(256) void qkv_norm_kernel(
    const float* __restrict__ x_cls, const float* __restrict__ x_reg,
    const float* __restrict__ W_cls, const float* __restrict__ W_reg,
    float* __restrict__ qn_cls, float* __restrict__ qn_reg,
    float* __restrict__ kct, float* __restrict__ krt,
    float* __restrict__ vnt, float* __restrict__ v_rm) {
  __shared__ float xs[4][256];
  __shared__ float res[4][768];
  __shared__ float inv_norm[96];

  const int n0 = blockIdx.x * 4;
  const int which = blockIdx.y;
  const int tid = threadIdx.x;
  const float* __restrict__ x = which ? x_reg : x_cls;
  const float* __restrict__ W = which ? W_reg : W_cls;

#pragma unroll
  for (int r = 0; r < 4; r++) xs[r][tid] = x[(n0 + r) * 256 + tid];
  __syncthreads();

  float acc[4][3];
#pragma unroll
  for (int r = 0; r < 4; r++) acc[r][0] = acc[r][1] = acc[r][2] = 0.f;

  for (int k = 0; k < 256; k++) {
    const float* __restrict__ wr = W + k * 768;
    const float w0 = wr[tid], w1 = wr[tid + 256], w2 = wr[tid + 512];
#pragma unroll
    for (int r = 0; r < 4; r++) {
      const float xv = xs[r][k];
      acc[r][0] += xv * w0;
      acc[r][1] += xv * w1;
      acc[r][2] += xv * w2;
    }
  }
#pragma unroll
  for (int r = 0; r < 4; r++) {
    res[r][tid] = acc[r][0];
    res[r][tid + 256] = acc[r][1];
    res[r][tid + 512] = acc[r][2];
  }
  __syncthreads();

  if (tid < 96) {
    const int r = tid / 24, grp = tid % 24;
    float ss = 0.f;
#pragma unroll
    for (int d = 0; d < HD; d++) {
      const float v = res[r][grp * 32 + d];
      ss += v * v;
    }
    inv_norm[tid] = 1.0f / (sqrtf(ss) + EPSF);
  }
  __syncthreads();

#pragma unroll
  for (int j = 0; j < 3; j++) {
    const int c = tid + j * 256;
    const int qkv = c >> 8, grp = c >> 5;
    const int h = grp & 7, d = c & 31;
    const int g = d >> 2, comp = d & 3;
#pragma unroll
    for (int r = 0; r < 4; r++) {
      const int n = n0 + r;
      const float val = res[r][c];
      const float nval = val * inv_norm[r * 24 + grp];
      if (qkv == 0) {
        (which ? qn_reg : qn_cls)[(h * N_TOK + n) * HD + d] = nval;
      } else if (qkv == 1) {
        (which ? krt : kct)[((h * 8 + g) * N_TOK + n) * 4 + comp] = nval;
      } else if (which == 0) {
        v_rm[(h * N_TOK + n) * HD + d] = val;
        vnt[((h * 8 + g) * N_TOK + n) * 4 + comp] = nval;
      }
    }
  }
}

// ---------------------------------------------------------------------------
// Kernel 2: 2 query rows per block. Fixed-shift softmax (score<=25 exactly,
// shift-invariant) -> no max pass. sim/raw/er in per-thread register slots.
// NO waves-per-eu clamp: the (256,4) hint empirically forced a 64-VGPR
// budget and gigabytes of scratch spill (rounds 3-4). Demand-driven
// allocation (round 2) produced zero spill.
// grid = 1000, block = 256
// ---------------------------------------------------------------------------
__global__ __launch_bounds__(256) void attn5_kernel(
    const float* __restrict__ qn_cls, const float* __restrict__ qn_reg,
    const float* __restrict__ kct, const float* __restrict__ krt,
    const float* __restrict__ vnt, const float* __restrict__ v_rm,
    float* __restrict__ out_x, float* __restrict__ out_sim) {
  __shared__ float s_attn[2 * N_TOK];
  __shared__ float4 part4[32][2][8];
  __shared__ float red[4];

  const int tid = threadIdx.x;
  const int i0 = blockIdx.x * 2;
  const int i1 = i0 + 1;
  const int bs = (i0 / 10) * 10;  // i0 even -> i0,i1 share the same decade

  // persistent per-thread accumulators (register slots, m = tid + 256*t)
  float sim0[NSLOT], sim1[NSLOT], raw0[NSLOT], raw1[NSLOT];
#pragma unroll
  for (int t = 0; t < NSLOT; t++) {
    sim0[t] = 0.f; sim1[t] = 0.f; raw0[t] = 0.f; raw1[t] = 0.f;
  }

  float q0[HD], q1[HD];          // wave-uniform -> SGPRs
  float er0[NSLOT], er1[NSLOT];  // reg-stream exp values (one pair only)

  for (int h = 0; h < NH; h++) {
    // ===== phase C: cls scores -> e = exp(s-25) -> s_attn (unnormalized) ===
    {
      const float* __restrict__ p0 = qn_cls + (size_t)(h * N_TOK + i0) * HD;
      const float* __restrict__ p1 = qn_cls + (size_t)(h * N_TOK + i1) * HD;
#pragma unroll
      for (int d = 0; d < HD; d++) { q0[d] = rfl(p0[d]); q1[d] = rfl(p1[d]); }
    }
    float ls0 = 0.f, ls1 = 0.f;
    {
      const float4* __restrict__ kt4 = (const float4*)kct + (size_t)h * 8 * N_TOK;
#pragma unroll
      for (int t = 0; t < NSLOT; t++) {
        const int m = tid + 256 * t;
        const bool valid = (t < 7) || (tid < NTAIL);
        const int mc = valid ? m : (N_TOK - 1);
        float d0 = 0.f, d1 = 0.f;
        DOT_BODY(kt4, mc, d0, d1);
        const float e0 = valid ? __expf(d0 * SCALE - SCALE) : 0.f;
        const float e1 = valid ? __expf(d1 * SCALE - SCALE) : 0.f;
        ls0 += e0; ls1 += e1;
        if (valid) {
          s_attn[m] = e0;
          s_attn[N_TOK + m] = e1;
        }
      }
    }
    const float S0c = block_sum256(ls0, red);
    const float S1c = block_sum256(ls1, red);
    const float n0c = 0.5f / S0c, n1c = 0.5f / S1c;

    // ===== phase R: reg scores -> er regs =====
    {
      const float* __restrict__ p0 = qn_reg + (size_t)(h * N_TOK + i0) * HD;
      const float* __restrict__ p1 = qn_reg + (size_t)(h * N_TOK + i1) * HD;
#pragma unroll
      for (int d = 0; d < HD; d++) { q0[d] = rfl(p0[d]); q1[d] = rfl(p1[d]); }
    }
    float lr0 = 0.f, lr1 = 0.f;
    {
      const float4* __restrict__ kt4 = (const float4*)krt + (size_t)h * 8 * N_TOK;
#pragma unroll
      for (int t = 0; t < NSLOT; t++) {
        const int m = tid + 256 * t;
        const bool valid = (t < 7) || (tid < NTAIL);
        const int mc = valid ? m : (N_TOK - 1);
        float d0 = 0.f, d1 = 0.f;
        DOT_BODY(kt4, mc, d0, d1);
        const float e0 = valid ? __expf(d0 * SCALE - SCALE) : 0.f;
        const float e1 = valid ? __expf(d1 * SCALE - SCALE) : 0.f;
        er0[t] = e0; er1[t] = e1;
        lr0 += e0; lr1 += e1;
      }
    }
    const float S0r = block_sum256(lr0, red);
    const float S1r = block_sum256(lr1, red);
    const float n0r = 0.5f / S0r, n1r = 0.5f / S1r;

    // ===== combine, mask, sim += =====
#pragma unroll
    for (int t = 0; t < NSLOT; t++) {
      const int m = tid + 256 * t;
      if ((t < 7) || (tid < NTAIL)) {
        float a0 = s_attn[m] * n0c + er0[t] * n0r;
        float a1 = s_attn[N_TOK + m] * n1c + er1[t] * n1r;
        if (m >= bs && m < bs + 9) {
          if (m != i0) a0 = 0.f;
          if (m != i1) a1 = 0.f;
        }
        s_attn[m] = a0;
        s_attn[N_TOK + m] = a1;
        sim0[t] += a0;
        sim1[t] += a1;
      }
    }

    // ===== phase V: vn cosine -> raw += =====
    {
#pragma unroll
      for (int d = 0; d < HD; d++) {
        const int g = d >> 2, comp = d & 3;
        q0[d] = rfl(vnt[((size_t)(h * 8 + g) * N_TOK + i0) * 4 + comp]);
        q1[d] = rfl(vnt[((size_t)(h * 8 + g) * N_TOK + i1) * 4 + comp]);
      }
      const float4* __restrict__ kt4 = (const float4*)vnt + (size_t)h * 8 * N_TOK;
#pragma unroll
      for (int t = 0; t < NSLOT; t++) {
        const int m = tid + 256 * t;
        const bool valid = (t < 7) || (tid < NTAIL);
        const int mc = valid ? m : (N_TOK - 1);
        float d0 = 0.f, d1 = 0.f;
        DOT_BODY(kt4, mc, d0, d1);
        if (valid) { raw0[t] += d0; raw1[t] += d1; }
      }
    }
    __syncthreads();  // s_attn final for this head

    // ===== attn @ V =====
    {
      const int g2 = tid & 7, slice = tid >> 3;
      const int m0 = slice * 63;
      const int mend = (m0 + 63 < N_TOK) ? (m0 + 63) : N_TOK;
      float4 a0acc = {0.f, 0.f, 0.f, 0.f}, a1acc = {0.f, 0.f, 0.f, 0.f};
      const float4* __restrict__ v4 = (const float4*)v_rm + (size_t)h * N_TOK * 8;
      for (int m = m0; m < mend; m++) {
        const float4 vv = v4[m * 8 + g2];
        const float a0 = s_attn[m];
        const float a1 = s_attn[N_TOK + m];
        a0acc.x += a0 * vv.x; a0acc.y += a0 * vv.y;
        a0acc.z += a0 * vv.z; a0acc.w += a0 * vv.w;
        a1acc.x += a1 * vv.x; a1acc.y += a1 * vv.y;
        a1acc.z += a1 * vv.z; a1acc.w += a1 * vv.w;
      }
      part4[slice][0][g2] = a0acc;
      part4[slice][1][g2] = a1acc;
    }
    __syncthreads();
    if (tid < 16) {
      const int q = tid >> 3, g = tid & 7;
      float4 s = {0.f, 0.f, 0.f, 0.f};
#pragma unroll 8
      for (int sl = 0; sl < 32; sl++) {
        const float4 p = part4[sl][q][g];
        s.x += p.x; s.y += p.y; s.z += p.z; s.w += p.w;
      }
      const int irow = q ? i1 : i0;
      *(float4*)(out_x + (size_t)irow * 512 + h * 32 + 4 * g) = s;
    } else if (tid >= 64 && tid < 128) {
      const int q = (tid - 64) >> 5, d = (tid - 64) & 31;
      const int irow = q ? i1 : i0;
      out_x[(size_t)irow * 512 + 256 + h * 32 + d] =
          v_rm[((size_t)h * N_TOK + irow) * HD + d];
    }
    __syncthreads();  // protect s_attn/part4 before next head
  }

  // ===== sim_round2 epilogue, from registers =====
#pragma unroll
  for (int q = 0; q < 2; q++) {
    const int irow = q ? i1 : i0;
    float* __restrict__ sim = q ? sim1 : sim0;
    float* __restrict__ raw = q ? raw1 : raw0;

    float lm = -1e30f;
#pragma unroll
    for (int t = 0; t < NSLOT; t++) {
      if ((t < 7) || (tid < NTAIL)) lm = fmaxf(lm, sim[t] * 0.125f);
    }
    const float M = block_max256(lm, red);

    float ls = 0.f;
#pragma unroll
    for (int t = 0; t < NSLOT; t++) {
      const bool valid = (t < 7) || (tid < NTAIL);
      const float e = valid ? __expf(sim[t] * 0.125f - M) : 0.f;
      sim[t] = e;
      ls += e;
    }
    const float S = block_sum256(ls, red);
    const float invS = 1.0f / S;

    float lms = 0.f;
#pragma unroll
    for (int t = 0; t < NSLOT; t++) {
      const bool valid = (t < 7) || (tid < NTAIL);
      const float p = sim[t] * invS;
      const float mp = (valid && (raw[t] * 0.125f > SIM_TH)) ? p : 0.f;
      sim[t] = mp;
      lms += mp;
    }
    const float MS = block_sum256(lms, red);
    const float invMS = 1.0f / (MS + EPSF);

#pragma unroll
    for (int t = 0; t < NSLOT; t++) {
      const int m = tid + 256 * t;
      if ((t < 7) || (tid < NTAIL)) {
        out_sim[(size_t)irow * N_TOK + m] = sim[t] * invMS;
      }
    }
  }
}

// ---------------------------------------------------------------------------
extern "C" void kernel_launch(void* const* d_in, const int* in_sizes, int n_in,
                              void* d_out, int out_size, void* d_ws,
                              size_t ws_size, hipStream_t stream) {
  const float* x_cls = (const float*)d_in[0];
  const float* x_reg = (const float*)d_in[1];
  const float* W_cls = (const float*)d_in[2];
  const float* W_reg = (const float*)d_in[3];

  float* ws = (float*)d_ws;
  const size_t seg = (size_t)NH * N_TOK * HD;  // 512000 floats
  float* qn_cls = ws;
  float* qn_reg = qn_cls + seg;
  float* kct = qn_reg + seg;
  float* krt = kct + seg;
  float* vnt = krt + seg;
  float* v_rm = vnt + seg;

  dim3 g1(500, 2);
  qkv_norm_kernel<<<g1, 256, 0, stream>>>(x_cls, x_reg, W_cls, W_reg, qn_cls,
                                          qn_reg, kct, krt, vnt, v_rm);

  float* out_x = (float*)d_out;                  // [2000, 512]
  float* out_sim = out_x + (size_t)N_TOK * 512;  // [2000, 2000]
  attn5_kernel<<<1000, 256, 0, stream>>>(qn_cls, qn_reg, kct, krt, vnt, v_rm,
                                         out_x, out_sim);
}